// Round 5
// baseline (215.276 us; speedup 1.0000x reference)
//
#include <hip/hip_runtime.h>
#include <math.h>

#define D 64
#define MAXNORM 0.999f
#define MAXNORM2 (0.999f * 0.999f)
#define MIN_NORM 1e-15f
#define TANH_CLIP 15.0f
#define CHUNK 1024

struct f4 { float x, y, z, w; };

__device__ __forceinline__ float frcp(float x) { return __builtin_amdgcn_rcpf(x); }
__device__ __forceinline__ float frsq(float x) { return __builtin_amdgcn_rsqf(x); }

__device__ __forceinline__ float dot8p(const f4& a0, const f4& a1,
                                       const f4& b0, const f4& b1) {
    return a0.x * b0.x + a0.y * b0.y + a0.z * b0.z + a0.w * b0.w +
           a1.x * b1.x + a1.y * b1.y + a1.z * b1.z + a1.w * b1.w;
}

__device__ __forceinline__ float rsum8(float v) {
    v += __shfl_xor(v, 1);
    v += __shfl_xor(v, 2);
    v += __shfl_xor(v, 4);
    return v;
}

// ---------------- fused setup: histogram (E edges) + row norms (N+32 rows) --------

__global__ void setup_kernel(const float* __restrict__ ego,
                             const float* __restrict__ rel,
                             const int* __restrict__ eidx,
                             int* __restrict__ cnt,
                             float* __restrict__ norms,
                             float* __restrict__ relnorm,
                             int N, int E, int hist_blocks) {
    int b = blockIdx.x;
    if (b < hist_blocks) {
        int e = b * 256 + threadIdx.x;
        if (e < E) atomicAdd(&cnt[eidx[e]], 1);
        return;
    }
    int wid = (b - hist_blocks) * 4 + (threadIdx.x >> 6);
    int lane = threadIdx.x & 63;
    const float* src;
    float* dst;
    if (wid < N)            { src = ego + (size_t)wid * D;       dst = norms + wid; }
    else if (wid < N + 32)  { src = rel + (size_t)(wid - N) * D; dst = relnorm + (wid - N); }
    else return;
    float v = src[lane];
    float s = v * v;
    s += __shfl_xor(s, 1);  s += __shfl_xor(s, 2);  s += __shfl_xor(s, 4);
    s += __shfl_xor(s, 8);  s += __shfl_xor(s, 16); s += __shfl_xor(s, 32);
    if (lane == 0) *dst = sqrtf(s);
}

// ---------------- single-kernel scan ----------------
// Each block independently computes its global prefix by summing cnt[0..base)
// (L2-resident, ~20 MB total extra reads — cheap), then scans its own chunk.

__global__ void scan_kernel(const int* __restrict__ cnt,
                            int* __restrict__ off,
                            int* __restrict__ cur, int N) {
    __shared__ int sdata[256];
    __shared__ int sprefix;
    int tid = threadIdx.x;
    int base0 = blockIdx.x * CHUNK;

    // phase A: prefix = sum of cnt[0..base0)  (base0 is a multiple of 1024)
    int psum = 0;
    const int4* cnt4 = (const int4*)cnt;
    for (int i = tid; i < (base0 >> 2); i += 256) {
        int4 v = cnt4[i];
        psum += v.x + v.y + v.z + v.w;
    }
    sdata[tid] = psum;
    __syncthreads();
    for (int o = 128; o > 0; o >>= 1) {
        if (tid < o) sdata[tid] += sdata[tid + o];
        __syncthreads();
    }
    if (tid == 0) sprefix = sdata[0];
    __syncthreads();
    int prefix = sprefix;
    __syncthreads();   // sdata reused below

    // phase B: scan own 1024-entry chunk
    int base = base0 + tid * 4;
    int v0 = (base + 0 < N) ? cnt[base + 0] : 0;
    int v1 = (base + 1 < N) ? cnt[base + 1] : 0;
    int v2 = (base + 2 < N) ? cnt[base + 2] : 0;
    int v3 = (base + 3 < N) ? cnt[base + 3] : 0;
    sdata[tid] = v0 + v1 + v2 + v3;
    __syncthreads();
    for (int o = 1; o < 256; o <<= 1) {
        int add = (tid >= o) ? sdata[tid - o] : 0;
        __syncthreads();
        sdata[tid] += add;
        __syncthreads();
    }
    int run = prefix + ((tid > 0) ? sdata[tid - 1] : 0);
    if (base + 0 < N) { off[base + 0] = run; cur[base + 0] = run; run += v0; }
    if (base + 1 < N) { off[base + 1] = run; cur[base + 1] = run; run += v1; }
    if (base + 2 < N) { off[base + 2] = run; cur[base + 2] = run; run += v2; }
    if (base + 3 < N) { off[base + 3] = run; cur[base + 3] = run; run += v3; }
}

// scatter packed (tail | type<<17): tail < 2^17, type < 32
__global__ void scatter_kernel(const int* __restrict__ eidx,
                               const int* __restrict__ etype,
                               int* __restrict__ cur,
                               int* __restrict__ sorted, int E) {
    int e = blockIdx.x * blockDim.x + threadIdx.x;
    if (e < E) {
        int pos = atomicAdd(&cur[eidx[e]], 1);
        sorted[pos] = eidx[E + e] | (etype[e] << 17);
    }
}

// ---------------- segmented aggregation: persistent waves, one head at a time ----
// All per-edge geometry reduced to scalar algebra over 3 dots (h.t, h.r, t.r):
// every intermediate vector is a linear combo of {p, t, r} with p = fp*h.

__global__ void __launch_bounds__(256) agg_kernel(
        const float* __restrict__ ego,
        const float* __restrict__ rel,
        const int* __restrict__ off,
        const int* __restrict__ cnt,
        const int* __restrict__ sorted,
        const float* __restrict__ norms,
        const float* __restrict__ relnorm,
        float* __restrict__ out,
        int N) {
    int wid0   = (blockIdx.x * blockDim.x + threadIdx.x) >> 6;
    int nwaves = (gridDim.x * blockDim.x) >> 6;
    int lane = threadIdx.x & 63;
    int slot = lane >> 3;     // 8 edge-slots per wave
    int sub  = lane & 7;      // 8 lanes per edge, 8 comps each

    for (int h = wid0; h < N; h += nwaves) {

    const float* hrow = ego + (size_t)h * D + sub * 8;
    f4 h0 = *(const f4*)(hrow);
    f4 h1 = *(const f4*)(hrow + 4);

    // head-only scalars
    float nh  = fmaxf(norms[h], MIN_NORM);
    float xh  = fminf(nh, TANH_CLIP);
    float eh  = __expf(-2.0f * xh);
    float fp  = (1.0f - eh) * frcp((1.0f + eh) * nh);   // p = fp * h
    float p2  = fp * fp * nh * nh;                      // tanh(nh)^2
    float tol = fmaxf(1.0f - p2, MIN_NORM);             // 2/lam
    float hl  = frcp(tol);                              // 0.5*lam

    int o = off[h];
    int c = cnt[h];
    f4 a0 = {0.f, 0.f, 0.f, 0.f}, a1 = {0.f, 0.f, 0.f, 0.f};
    float accP = 0.f;

    for (int i = slot; i < c; i += 8) {
        int pk   = sorted[o + i];
        int tail = pk & 0x1FFFF;
        int type = pk >> 17;

        const float* trow = ego + (size_t)tail * D + sub * 8;
        f4 t0 = *(const f4*)(trow);
        f4 t1 = *(const f4*)(trow + 4);
        const float* rrow = rel + (size_t)type * D + sub * 8;
        f4 r0 = *(const f4*)(rrow);
        f4 r1 = *(const f4*)(rrow + 4);
        float nt = norms[tail];
        float nr = relnorm[type];

        // the only 3 wave reductions per edge
        float d_ht = rsum8(dot8p(h0, h1, t0, t1));
        float d_hr = rsum8(dot8p(h0, h1, r0, r1));
        float d_tr = rsum8(dot8p(t0, t1, r0, r1));

        float t2 = nt * nt, r2 = nr * nr;
        float pt = fp * d_ht;                  // p.t
        float pr = fp * d_hr;                  // p.r

        // hyper_tail = mobius(p, yt), yt = ft*t ; ft = tanh(hl*nt)/nt (one rcp)
        float ntc = fmaxf(nt, MIN_NORM);
        float xt  = fminf(hl * ntc, TANH_CLIP);
        float et  = __expf(-2.0f * xt);
        float ft  = (1.0f - et) * frcp((1.0f + et) * ntc);
        float yt2 = ft * ft * t2;
        float pyt = ft * pt;
        float at  = 1.0f + 2.0f * pyt + yt2;
        float invt = frcp(fmaxf(1.0f + 2.0f * pyt + p2 * yt2, MIN_NORM));
        float At = at * invt;                  // coeff on p
        float Bt = tol * invt * ft;            // coeff on raw t

        // hyper_rel = mobius(p, yr), yr = fr*r
        float nrc = fmaxf(nr, MIN_NORM);
        float xr  = fminf(hl * nrc, TANH_CLIP);
        float er  = __expf(-2.0f * xr);
        float fr  = (1.0f - er) * frcp((1.0f + er) * nrc);
        float yr2 = fr * fr * r2;
        float pyr = fr * pr;
        float ar  = 1.0f + 2.0f * pyr + yr2;
        float invr = frcp(fmaxf(1.0f + 2.0f * pyr + p2 * yr2, MIN_NORM));
        float Ar = ar * invr;
        float Br = tol * invr * fr;

        // m = mobius(ht, hr) where ht = At*p+Bt*t, hr = Ar*p+Br*r
        float x2 = At * At * p2 + 2.0f * At * Bt * pt + Bt * Bt * t2;
        float y2 = Ar * Ar * p2 + 2.0f * Ar * Br * pr + Br * Br * r2;
        float xy = At * Ar * p2 + At * Br * pr + Ar * Bt * pt + Bt * Br * d_tr;
        float am = 1.0f + 2.0f * xy + y2;
        float bm = 1.0f - x2;
        float invm = frcp(fmaxf(1.0f + 2.0f * xy + x2 * y2, MIN_NORM));
        float al = (am * At + bm * Ar) * invm; // m coeff on p
        float be = am * Bt * invm;             // on t
        float ga = bm * Br * invm;             // on r

        float m2 = al * al * p2 + be * be * t2 + ga * ga * r2 +
                   2.0f * (al * be * pt + al * ga * pr + be * ga * d_tr);
        m2 = fmaxf(m2, 1e-30f);

        // project
        float scp = (m2 > MAXNORM2) ? MAXNORM * frsq(m2) : 1.0f;
        al *= scp; be *= scp; ga *= scp;
        m2 *= scp * scp;

        // s = mobius(-p, m)
        float pm   = al * p2 + be * pt + ga * pr;
        float invs = frcp(fmaxf(1.0f - 2.0f * pm + p2 * m2, MIN_NORM));
        float sp   = -(1.0f - 2.0f * pm + m2) * invs;  // s coeff on p (direct)
        float smm  = tol * invs;                       // s coeff on m
        float u = sp + smm * al;
        float v = smm * be;
        float w = smm * ga;

        float s2 = u * u * p2 + v * v * t2 + w * w * r2 +
                   2.0f * (u * v * pt + u * w * pr + v * w * d_tr);
        s2 = fmaxf(s2, 1e-30f);
        float irs = frsq(s2);
        float ns  = fminf(s2 * irs, 1.0f - 1e-7f);     // |s|, clipped for artanh
        float art = 0.5f * __logf((1.0f + ns) * frcp(1.0f - ns));
        float sc  = tol * art * irs;                   // (2/lam)*artanh(ns)/|s|

        // res = sc*(u*p + v*t + w*r); accumulate
        float ct = sc * v, cr = sc * w;
        accP += sc * u;
        a0.x += ct * t0.x + cr * r0.x;  a0.y += ct * t0.y + cr * r0.y;
        a0.z += ct * t0.z + cr * r0.z;  a0.w += ct * t0.w + cr * r0.w;
        a1.x += ct * t1.x + cr * r1.x;  a1.y += ct * t1.y + cr * r1.y;
        a1.z += ct * t1.z + cr * r1.z;  a1.w += ct * t1.w + cr * r1.w;
    }

    // reduce the 8 slots (lanes l, l^8, l^16, l^32)
    #define RED(x) x += __shfl_xor(x, 8); x += __shfl_xor(x, 16); x += __shfl_xor(x, 32);
    RED(accP)
    RED(a0.x) RED(a0.y) RED(a0.z) RED(a0.w)
    RED(a1.x) RED(a1.y) RED(a1.z) RED(a1.w)
    #undef RED

    if (slot == 0) {
        float invc = frcp(fmaxf((float)c, 1.0f));
        float hp = accP * fp * invc;               // p-coeff back to h-units
        f4 o0, o1;
        o0.x = hp * h0.x + a0.x * invc;  o0.y = hp * h0.y + a0.y * invc;
        o0.z = hp * h0.z + a0.z * invc;  o0.w = hp * h0.w + a0.w * invc;
        o1.x = hp * h1.x + a1.x * invc;  o1.y = hp * h1.y + a1.y * invc;
        o1.z = hp * h1.z + a1.z * invc;  o1.w = hp * h1.w + a1.w * invc;
        float* orow = out + (size_t)h * D + sub * 8;
        *(f4*)(orow)     = o0;
        *(f4*)(orow + 4) = o1;
    }

    // zero accumulators for next head handled implicitly (re-declared per iter)
    }
}

extern "C" void kernel_launch(void* const* d_in, const int* in_sizes, int n_in,
                              void* d_out, int out_size, void* d_ws, size_t ws_size,
                              hipStream_t stream) {
    const float* ego  = (const float*)d_in[0];
    const int*   eidx = (const int*)d_in[1];
    const int*   etyp = (const int*)d_in[2];
    const float* rel  = (const float*)d_in[3];
    float* out = (float*)d_out;

    int E = in_sizes[1] / 2;          // 800000
    int N = in_sizes[0] / D;          // 100000
    int NB = (N + CHUNK - 1) / CHUNK;

    // workspace layout
    int* cnt      = (int*)d_ws;           // N
    int* off      = cnt + N;              // N
    int* cur      = off + N;              // N
    int* sorted   = cur + N;              // E
    float* norms   = (float*)(sorted + E);     // N
    float* relnorm = norms + N;                // 32

    hipMemsetAsync(cnt, 0, (size_t)N * sizeof(int), stream);

    const int tpb = 256;
    int hist_blocks = (E + tpb - 1) / tpb;
    int norm_blocks = (N + 32 + 3) / 4;

    setup_kernel<<<hist_blocks + norm_blocks, tpb, 0, stream>>>(
        ego, rel, eidx, cnt, norms, relnorm, N, E, hist_blocks);
    scan_kernel<<<NB, tpb, 0, stream>>>(cnt, off, cur, N);
    scatter_kernel<<<hist_blocks, tpb, 0, stream>>>(eidx, etyp, cur, sorted, E);

    agg_kernel<<<4096, tpb, 0, stream>>>(ego, rel, off, cnt, sorted,
                                         norms, relnorm, out, N);
}

// Round 6
// 175.317 us; speedup vs baseline: 1.2279x; 1.2279x over previous
//
#include <hip/hip_runtime.h>
#include <math.h>

#define D 64
#define MAXNORM 0.999f
#define MAXNORM2 (0.999f * 0.999f)
#define MIN_NORM 1e-15f
#define TANH_CLIP 15.0f
#define CHUNK 1024

struct f4 { float x, y, z, w; };

__device__ __forceinline__ float frcp(float x) { return __builtin_amdgcn_rcpf(x); }
__device__ __forceinline__ float frsq(float x) { return __builtin_amdgcn_rsqf(x); }

__device__ __forceinline__ float dot8p(const f4& a0, const f4& a1,
                                       const f4& b0, const f4& b1) {
    return a0.x * b0.x + a0.y * b0.y + a0.z * b0.z + a0.w * b0.w +
           a1.x * b1.x + a1.y * b1.y + a1.z * b1.z + a1.w * b1.w;
}

__device__ __forceinline__ float rsum8(float v) {
    v += __shfl_xor(v, 1);
    v += __shfl_xor(v, 2);
    v += __shfl_xor(v, 4);
    return v;
}

// ------- fused setup: histogram+rank (E edges) + row norms (N+32 rows) -------

__global__ void setup_kernel(const float* __restrict__ ego,
                             const float* __restrict__ rel,
                             const int* __restrict__ eidx,
                             int* __restrict__ cnt,
                             int* __restrict__ rank,
                             float* __restrict__ norms,
                             float* __restrict__ relnorm,
                             int N, int E, int hist_blocks) {
    int b = blockIdx.x;
    if (b < hist_blocks) {
        int e = b * 256 + threadIdx.x;
        if (e < E) rank[e] = atomicAdd(&cnt[eidx[e]], 1);
        return;
    }
    int wid = (b - hist_blocks) * 4 + (threadIdx.x >> 6);
    int lane = threadIdx.x & 63;
    const float* src;
    float* dst;
    if (wid < N)            { src = ego + (size_t)wid * D;       dst = norms + wid; }
    else if (wid < N + 32)  { src = rel + (size_t)(wid - N) * D; dst = relnorm + (wid - N); }
    else return;
    float v = src[lane];
    float s = v * v;
    s += __shfl_xor(s, 1);  s += __shfl_xor(s, 2);  s += __shfl_xor(s, 4);
    s += __shfl_xor(s, 8);  s += __shfl_xor(s, 16); s += __shfl_xor(s, 32);
    if (lane == 0) *dst = sqrtf(s);
}

// ---------------- single-kernel scan ----------------

__global__ void scan_kernel(const int* __restrict__ cnt,
                            int* __restrict__ off, int N) {
    __shared__ int sdata[256];
    __shared__ int sprefix;
    int tid = threadIdx.x;
    int base0 = blockIdx.x * CHUNK;

    // phase A: prefix = sum of cnt[0..base0)
    int psum = 0;
    const int4* cnt4 = (const int4*)cnt;
    for (int i = tid; i < (base0 >> 2); i += 256) {
        int4 v = cnt4[i];
        psum += v.x + v.y + v.z + v.w;
    }
    sdata[tid] = psum;
    __syncthreads();
    for (int o = 128; o > 0; o >>= 1) {
        if (tid < o) sdata[tid] += sdata[tid + o];
        __syncthreads();
    }
    if (tid == 0) sprefix = sdata[0];
    __syncthreads();
    int prefix = sprefix;
    __syncthreads();

    // phase B: scan own 1024-entry chunk
    int base = base0 + tid * 4;
    int v0 = (base + 0 < N) ? cnt[base + 0] : 0;
    int v1 = (base + 1 < N) ? cnt[base + 1] : 0;
    int v2 = (base + 2 < N) ? cnt[base + 2] : 0;
    int v3 = (base + 3 < N) ? cnt[base + 3] : 0;
    sdata[tid] = v0 + v1 + v2 + v3;
    __syncthreads();
    for (int o = 1; o < 256; o <<= 1) {
        int add = (tid >= o) ? sdata[tid - o] : 0;
        __syncthreads();
        sdata[tid] += add;
        __syncthreads();
    }
    int run = prefix + ((tid > 0) ? sdata[tid - 1] : 0);
    if (base + 0 < N) { off[base + 0] = run; run += v0; }
    if (base + 1 < N) { off[base + 1] = run; run += v1; }
    if (base + 2 < N) { off[base + 2] = run; run += v2; }
    if (base + 3 < N) { off[base + 3] = run; run += v3; }
}

// atomic-free scatter: pos = off[head] + rank[e]; payload = tail | type<<17
__global__ void scatter_kernel(const int* __restrict__ eidx,
                               const int* __restrict__ etype,
                               const int* __restrict__ rank,
                               const int* __restrict__ off,
                               int* __restrict__ sorted, int E) {
    int e = blockIdx.x * blockDim.x + threadIdx.x;
    if (e < E) {
        int pos = off[eidx[e]] + rank[e];
        sorted[pos] = eidx[E + e] | (etype[e] << 17);
    }
}

// ---------------- segmented aggregation: one wave per head ----------------
// Per-edge geometry is scalar algebra over 3 dots (h.t, h.r, t.r); all norms
// of Mobius sums use |x(+)y|^2 = (|x|^2 + 2 x.y + |y|^2) * inv_denominator.

__global__ void __launch_bounds__(256) agg_kernel(
        const float* __restrict__ ego,
        const float* __restrict__ rel,
        const int* __restrict__ off,
        const int* __restrict__ cnt,
        const int* __restrict__ sorted,
        const float* __restrict__ norms,
        const float* __restrict__ relnorm,
        float* __restrict__ out,
        int N) {
    int wid = (blockIdx.x * blockDim.x + threadIdx.x) >> 6;   // one wave per head
    if (wid >= N) return;
    int lane = threadIdx.x & 63;
    int slot = lane >> 3;     // 8 edge-slots per wave
    int sub  = lane & 7;      // 8 lanes per edge, 8 comps each

    int h = wid;
    const float* hrow = ego + (size_t)h * D + sub * 8;
    f4 h0 = *(const f4*)(hrow);
    f4 h1 = *(const f4*)(hrow + 4);

    // head-only scalars
    float nh  = fmaxf(norms[h], MIN_NORM);
    float xh  = fminf(nh, TANH_CLIP);
    float eh  = __expf(-2.0f * xh);
    float fp  = (1.0f - eh) * frcp((1.0f + eh) * nh);   // p = fp * h
    float p2  = fp * fp * nh * nh;                      // tanh(nh)^2
    float tol = fmaxf(1.0f - p2, MIN_NORM);             // 2/lam
    float hl  = frcp(tol);                              // 0.5*lam

    int o = off[h];
    int c = cnt[h];
    f4 a0 = {0.f, 0.f, 0.f, 0.f}, a1 = {0.f, 0.f, 0.f, 0.f};
    float accP = 0.f;

    for (int i = slot; i < c; i += 8) {
        int pk   = sorted[o + i];
        int tail = pk & 0x1FFFF;
        int type = pk >> 17;

        const float* trow = ego + (size_t)tail * D + sub * 8;
        f4 t0 = *(const f4*)(trow);
        f4 t1 = *(const f4*)(trow + 4);
        const float* rrow = rel + (size_t)type * D + sub * 8;
        f4 r0 = *(const f4*)(rrow);
        f4 r1 = *(const f4*)(rrow + 4);
        float nt = norms[tail];
        float nr = relnorm[type];

        // the only 3 wave reductions per edge
        float d_ht = rsum8(dot8p(h0, h1, t0, t1));
        float d_hr = rsum8(dot8p(h0, h1, r0, r1));
        float d_tr = rsum8(dot8p(t0, t1, r0, r1));

        float t2 = nt * nt, r2 = nr * nr;
        float pt = fp * d_ht;                  // p.t
        float pr = fp * d_hr;                  // p.r

        // hyper_tail = p (+) yt, yt = ft*t
        float ntc = fmaxf(nt, MIN_NORM);
        float xt  = fminf(hl * ntc, TANH_CLIP);
        float et  = __expf(-2.0f * xt);
        float ft  = (1.0f - et) * frcp((1.0f + et) * ntc);
        float yt2 = ft * ft * t2;
        float pyt = ft * pt;
        float invt = frcp(fmaxf(1.0f + 2.0f * pyt + p2 * yt2, MIN_NORM));
        float At = (1.0f + 2.0f * pyt + yt2) * invt;   // coeff on p
        float Bt = tol * invt * ft;                    // coeff on raw t
        float x2 = (p2 + 2.0f * pyt + yt2) * invt;     // |ht|^2 (identity)

        // hyper_rel = p (+) yr, yr = fr*r
        float nrc = fmaxf(nr, MIN_NORM);
        float xr  = fminf(hl * nrc, TANH_CLIP);
        float er  = __expf(-2.0f * xr);
        float fr  = (1.0f - er) * frcp((1.0f + er) * nrc);
        float yr2 = fr * fr * r2;
        float pyr = fr * pr;
        float invr = frcp(fmaxf(1.0f + 2.0f * pyr + p2 * yr2, MIN_NORM));
        float Ar = (1.0f + 2.0f * pyr + yr2) * invr;
        float Br = tol * invr * fr;
        float y2 = (p2 + 2.0f * pyr + yr2) * invr;     // |hr|^2

        // m = ht (+) hr, ht = At*p+Bt*t, hr = Ar*p+Br*r
        float xy = At * Ar * p2 + At * Br * pr + Ar * Bt * pt + Bt * Br * d_tr;
        float am = 1.0f + 2.0f * xy + y2;
        float bm = 1.0f - x2;
        float invm = frcp(fmaxf(1.0f + 2.0f * xy + x2 * y2, MIN_NORM));
        float al = (am * At + bm * Ar) * invm; // m coeff on p
        float be = am * Bt * invm;             // on t
        float ga = bm * Br * invm;             // on r
        float m2 = (x2 + 2.0f * xy + y2) * invm;       // |m|^2 (identity)
        m2 = fmaxf(m2, 1e-30f);

        // project
        float scp = (m2 > MAXNORM2) ? MAXNORM * frsq(m2) : 1.0f;
        al *= scp; be *= scp; ga *= scp;
        m2 *= scp * scp;

        // s = (-p) (+) m
        float pm   = al * p2 + be * pt + ga * pr;
        float invs = frcp(fmaxf(1.0f - 2.0f * pm + p2 * m2, MIN_NORM));
        float sp   = -(1.0f - 2.0f * pm + m2) * invs;  // s coeff on p
        float smm  = tol * invs;                       // s coeff on m
        float u = sp + smm * al;
        float v = smm * be;
        float w = smm * ga;
        float s2 = (p2 - 2.0f * pm + m2) * invs;       // |s|^2 (identity)
        s2 = fmaxf(s2, 1e-30f);

        float irs = frsq(s2);
        float ns  = fminf(s2 * irs, 1.0f - 1e-7f);     // |s|
        float art = 0.5f * __logf((1.0f + ns) * frcp(1.0f - ns));
        float sc  = tol * art * irs;                   // (2/lam)*artanh(ns)/|s|

        // res = sc*(u*p + v*t + w*r); accumulate
        float ct = sc * v, cr = sc * w;
        accP += sc * u;
        a0.x += ct * t0.x + cr * r0.x;  a0.y += ct * t0.y + cr * r0.y;
        a0.z += ct * t0.z + cr * r0.z;  a0.w += ct * t0.w + cr * r0.w;
        a1.x += ct * t1.x + cr * r1.x;  a1.y += ct * t1.y + cr * r1.y;
        a1.z += ct * t1.z + cr * r1.z;  a1.w += ct * t1.w + cr * r1.w;
    }

    // reduce the 8 slots (lanes l, l^8, l^16, l^32)
    #define RED(x) x += __shfl_xor(x, 8); x += __shfl_xor(x, 16); x += __shfl_xor(x, 32);
    RED(accP)
    RED(a0.x) RED(a0.y) RED(a0.z) RED(a0.w)
    RED(a1.x) RED(a1.y) RED(a1.z) RED(a1.w)
    #undef RED

    if (slot == 0) {
        float invc = frcp(fmaxf((float)c, 1.0f));
        float hp = accP * fp * invc;               // p-coeff back to h-units
        f4 o0, o1;
        o0.x = hp * h0.x + a0.x * invc;  o0.y = hp * h0.y + a0.y * invc;
        o0.z = hp * h0.z + a0.z * invc;  o0.w = hp * h0.w + a0.w * invc;
        o1.x = hp * h1.x + a1.x * invc;  o1.y = hp * h1.y + a1.y * invc;
        o1.z = hp * h1.z + a1.z * invc;  o1.w = hp * h1.w + a1.w * invc;
        float* orow = out + (size_t)h * D + sub * 8;
        *(f4*)(orow)     = o0;
        *(f4*)(orow + 4) = o1;
    }
}

extern "C" void kernel_launch(void* const* d_in, const int* in_sizes, int n_in,
                              void* d_out, int out_size, void* d_ws, size_t ws_size,
                              hipStream_t stream) {
    const float* ego  = (const float*)d_in[0];
    const int*   eidx = (const int*)d_in[1];
    const int*   etyp = (const int*)d_in[2];
    const float* rel  = (const float*)d_in[3];
    float* out = (float*)d_out;

    int E = in_sizes[1] / 2;          // 800000
    int N = in_sizes[0] / D;          // 100000
    int NB = (N + CHUNK - 1) / CHUNK;

    // workspace layout (ints/floats, ~7.6 MB total)
    int* cnt      = (int*)d_ws;           // N
    int* off      = cnt + N;              // N
    int* rank     = off + N;              // E
    int* sorted   = rank + E;             // E
    float* norms   = (float*)(sorted + E);     // N
    float* relnorm = norms + N;                // 32

    hipMemsetAsync(cnt, 0, (size_t)N * sizeof(int), stream);

    const int tpb = 256;
    int hist_blocks = (E + tpb - 1) / tpb;
    int norm_blocks = (N + 32 + 3) / 4;

    setup_kernel<<<hist_blocks + norm_blocks, tpb, 0, stream>>>(
        ego, rel, eidx, cnt, rank, norms, relnorm, N, E, hist_blocks);
    scan_kernel<<<NB, tpb, 0, stream>>>(cnt, off, N);
    scatter_kernel<<<hist_blocks, tpb, 0, stream>>>(eidx, etyp, rank, off, sorted, E);

    int nblocks = (N + 3) / 4;            // 4 waves (heads) per 256-block
    agg_kernel<<<nblocks, tpb, 0, stream>>>(ego, rel, off, cnt, sorted,
                                            norms, relnorm, out, N);
}